// Round 1
// baseline (275.265 us; speedup 1.0000x reference)
//
#include <hip/hip_runtime.h>

#define B 8
#define E 2000
#define NTRI 10000
#define NRELS 25
#define KT 16
#define TT 3
#define LL 32
#define TAU1 10.0f

__device__ __forceinline__ float clip01(float x) { return fminf(fmaxf(x, 0.0f), 1.0f); }

// Find the single nonzero per row (mode=1: out[row]=col) or per column (mode=0: out[col]=row)
// of a dense row-major [R,C] matrix, read flat as float4 (total must be %4==0).
__global__ void extract_onehot(const float4* __restrict__ m, int total4, int C,
                               int* __restrict__ out, int mode) {
    int stride = gridDim.x * blockDim.x;
    for (int i = blockIdx.x * blockDim.x + threadIdx.x; i < total4; i += stride) {
        float4 v = m[i];
        int f = i * 4;
        if (v.x != 0.0f) { int a = f + 0, r = a / C, c = a - r * C; if (mode == 0) out[c] = r; else out[r] = c; }
        if (v.y != 0.0f) { int a = f + 1, r = a / C, c = a - r * C; if (mode == 0) out[c] = r; else out[r] = c; }
        if (v.z != 0.0f) { int a = f + 2, r = a / C, c = a - r * C; if (mode == 0) out[c] = r; else out[r] = c; }
        if (v.w != 0.0f) { int a = f + 3, r = a / C, c = a - r * C; if (mode == 0) out[c] = r; else out[r] = c; }
    }
}

// hidden_base[e,r] = 1 if any triple (tail=e, rel=r<24); hxflag[b,r] = 1 if ent[b] heads a rel-r triple.
__global__ void scatter_flags(const int* __restrict__ heads, const int* __restrict__ tails,
                              const int* __restrict__ rels, const int* __restrict__ ent,
                              float* __restrict__ hidden_base, float* __restrict__ hxflag) {
    int j = blockIdx.x * blockDim.x + threadIdx.x;
    if (j >= NTRI) return;
    int r = rels[j];
    if (r < NRELS - 1) hidden_base[tails[j] * (NRELS - 1) + r] = 1.0f;
    int h = heads[j];
#pragma unroll
    for (int b = 0; b < B; b++)
        if (ent[b] == h) hxflag[b * NRELS + r] = 1.0f;
}

// One block, 256 threads: softmax(w) rows, tanh(weight), hidden_x0[b,l] (t=0 only).
__global__ void precompute_small(const float* __restrict__ w, const float* __restrict__ weight,
                                 const float* __restrict__ h_x, const float* __restrict__ h_x_type,
                                 const float* __restrict__ alpha, const float* __restrict__ beta,
                                 const float* __restrict__ alpha_x, const float* __restrict__ beta_x,
                                 const int* __restrict__ ent, const int* __restrict__ tidx,
                                 const float* __restrict__ hxflag,
                                 float* __restrict__ wp, float* __restrict__ tanhw,
                                 float* __restrict__ hidden_x0) {
    int t = threadIdx.x;
    if (t < TT * LL) {  // softmax over NRELS for row t of w (flattened [T,L])
        const float* row = w + t * NRELS;
        float mx = row[0];
        for (int r = 1; r < NRELS; r++) mx = fmaxf(mx, row[r]);
        float ex[NRELS]; float s = 0.0f;
        for (int r = 0; r < NRELS; r++) { ex[r] = expf(row[r] - mx); s += ex[r]; }
        float inv = 1.0f / s;
        for (int r = 0; r < NRELS; r++) wp[t * NRELS + r] = ex[r] * inv;
    }
    if (t < LL) tanhw[t] = tanhf(weight[t]);
    // hidden_x0 for all (b,l): t = b*32 + l
    int b = t >> 5, l = t & 31;
    float a  = clip01(alpha[l] / TAU1);   // alpha[0,l]
    float bb = clip01(beta[l]  / TAU1);
    float htx = clip01(h_x_type[l * KT + tidx[ent[b]]] / TAU1);
    float hxlin = 0.0f;
    for (int i = 0; i < NRELS - 1; i++) {
        int pi = (i < 12) ? (12 + i) : (i - 12);  // concat(hx_raw[:,12:24], hx_raw[:,0:12])
        hxlin += hxflag[b * NRELS + pi] * clip01(h_x[l * (NRELS - 1) + i] / TAU1);
    }
    float ax = clip01(alpha_x[l] / TAU1), bx = clip01(beta_x[l] / TAU1);
    float gate = 1.0f - clip01(ax + bx);
    hidden_x0[t] = clip01(a * htx + bb * hxlin) + gate;
}

// hidden[(t*L+l)*E + e] = clip01(a*htp[tidx[e]] + b*dot(hidden_base[e,:], hp)) + (1-clip01(a+b))
__global__ void hidden_kernel(const float* __restrict__ h, const float* __restrict__ h_type,
                              const float* __restrict__ alpha, const float* __restrict__ beta,
                              const int* __restrict__ tidx, const float* __restrict__ hidden_base,
                              float* __restrict__ hidden) {
    int idx = blockIdx.x * blockDim.x + threadIdx.x;
    if (idx >= TT * LL * E) return;
    int e = idx % E;
    int tl = idx / E;
    float a  = clip01(alpha[tl] / TAU1);
    float bb = clip01(beta[tl]  / TAU1);
    const float* hb = hidden_base + e * (NRELS - 1);
    const float* hp = h + tl * (NRELS - 1);
    float dot = 0.0f;
#pragma unroll
    for (int i = 0; i < NRELS - 1; i++) dot += hb[i] * clip01(hp[i] / TAU1);
    float htp = clip01(h_type[tl * KT + tidx[e]] / TAU1);
    hidden[idx] = clip01(a * htp + bb * dot) + (1.0f - clip01(a + bb));
}

// One block per (b,l): s_out[tails[j]] += s_prev[heads[j]] * wp[l, rels[j]]; scale by hidden (and hidden_x0 at t=0).
__global__ void __launch_bounds__(256) prop_kernel(
        const float* __restrict__ sprev, const int* __restrict__ heads,
        const int* __restrict__ tails, const int* __restrict__ rels,
        const int* __restrict__ ent, const float* __restrict__ wp_t,
        const float* __restrict__ hidden_t, const float* __restrict__ hidden_x0,
        float* __restrict__ sout, int is_first) {
    __shared__ float prev[E];
    __shared__ float acc[E];
    int blk = blockIdx.x;
    int b = blk / LL, l = blk % LL;
    int tid = threadIdx.x;
    if (is_first) {
        int eb = ent[b];
        for (int e = tid; e < E; e += 256) prev[e] = (e == eb) ? 1.0f : 0.0f;
    } else {
        const float* sp = sprev + (size_t)blk * E;
        for (int e = tid; e < E; e += 256) prev[e] = sp[e];
    }
    for (int e = tid; e < E; e += 256) acc[e] = 0.0f;
    __syncthreads();
    const float* wrow = wp_t + l * NRELS;
    for (int j = tid; j < NTRI; j += 256) {
        float p = prev[heads[j]];
        if (p != 0.0f) {
            p *= wrow[rels[j]];
            atomicAdd(&acc[tails[j]], p);
        }
    }
    __syncthreads();
    float extra = is_first ? hidden_x0[blk] : 1.0f;
    const float* hrow = hidden_t + (size_t)l * E;
    float* so = sout + (size_t)blk * E;
    for (int e = tid; e < E; e += 256) so[e] = acc[e] * hrow[e] * extra;
}

__global__ void out_kernel(const float* __restrict__ s, const float* __restrict__ tanhw,
                           float* __restrict__ out) {
    int idx = blockIdx.x * blockDim.x + threadIdx.x;
    if (idx >= B * E) return;
    int b = idx / E, e = idx % E;
    float accv = 0.0f;
#pragma unroll
    for (int l = 0; l < LL; l++) accv += s[((size_t)b * LL + l) * E + e] * tanhw[l];
    out[idx] = accv;
}

extern "C" void kernel_launch(void* const* d_in, const int* in_sizes, int n_in,
                              void* d_out, int out_size, void* d_ws, size_t ws_size,
                              hipStream_t stream) {
    const float* input_x  = (const float*)d_in[0];
    const float* type_mat = (const float*)d_in[1];
    const float* e2triple = (const float*)d_in[2];
    const float* triple2e = (const float*)d_in[3];
    const float* triple2r = (const float*)d_in[4];
    const float* w        = (const float*)d_in[5];
    const float* weight   = (const float*)d_in[6];
    const float* h        = (const float*)d_in[7];
    const float* h_x      = (const float*)d_in[8];
    const float* h_type   = (const float*)d_in[9];
    const float* h_x_type = (const float*)d_in[10];
    const float* alpha    = (const float*)d_in[11];
    const float* beta     = (const float*)d_in[12];
    const float* alpha_x  = (const float*)d_in[13];
    const float* beta_x   = (const float*)d_in[14];
    // d_in[15] = flag, unused (reference ignores it on this path)

    char* ws = (char*)d_ws;
    size_t off = 0;
    auto alloc = [&](size_t bytes) -> void* {
        void* p = ws + off;
        off += (bytes + 255) & ~(size_t)255;
        return p;
    };
    float* hidden_base = (float*)alloc(E * (NRELS - 1) * sizeof(float));  // 192000
    float* hxflag      = (float*)alloc(B * NRELS * sizeof(float));
    size_t zero_bytes = off;  // regions that must start at 0 (scatter targets)
    int*   heads  = (int*)alloc(NTRI * sizeof(int));
    int*   tails  = (int*)alloc(NTRI * sizeof(int));
    int*   rels   = (int*)alloc(NTRI * sizeof(int));
    int*   ent    = (int*)alloc(B * sizeof(int));
    int*   tidx   = (int*)alloc(E * sizeof(int));
    float* wp     = (float*)alloc(TT * LL * NRELS * sizeof(float));
    float* tanhw  = (float*)alloc(LL * sizeof(float));
    float* hx0    = (float*)alloc(B * LL * sizeof(float));
    float* hidden = (float*)alloc((size_t)TT * LL * E * sizeof(float));
    float* sA     = (float*)alloc((size_t)B * LL * E * sizeof(float));
    float* sB     = (float*)alloc((size_t)B * LL * E * sizeof(float));
    (void)ws_size; (void)in_sizes; (void)n_in; (void)out_size;

    hipMemsetAsync(ws, 0, zero_bytes, stream);

    // Index extraction (HBM-bound: 161 MB)
    auto launch_extract = [&](const float* m, int total, int C, int* outp, int mode) {
        int total4 = total / 4;
        int nb = (total4 + 255) / 256;
        if (nb > 8192) nb = 8192;
        extract_onehot<<<nb, 256, 0, stream>>>((const float4*)m, total4, C, outp, mode);
    };
    launch_extract(e2triple, E * NTRI, NTRI, heads, 0);   // out[col]=row
    launch_extract(triple2e, NTRI * E, E, tails, 1);      // out[row]=col
    launch_extract(triple2r, NTRI * NRELS, NRELS, rels, 1);
    launch_extract(input_x, B * E, E, ent, 1);
    launch_extract(type_mat, E * KT, KT, tidx, 1);

    scatter_flags<<<(NTRI + 255) / 256, 256, 0, stream>>>(heads, tails, rels, ent,
                                                          hidden_base, hxflag);

    precompute_small<<<1, 256, 0, stream>>>(w, weight, h_x, h_x_type, alpha, beta,
                                            alpha_x, beta_x, ent, tidx, hxflag,
                                            wp, tanhw, hx0);

    hidden_kernel<<<(TT * LL * E + 255) / 256, 256, 0, stream>>>(h, h_type, alpha, beta,
                                                                 tidx, hidden_base, hidden);

    // T=3 propagation rounds
    prop_kernel<<<B * LL, 256, 0, stream>>>(nullptr, heads, tails, rels, ent,
                                            wp + 0 * LL * NRELS, hidden + (size_t)0 * LL * E,
                                            hx0, sA, 1);
    prop_kernel<<<B * LL, 256, 0, stream>>>(sA, heads, tails, rels, ent,
                                            wp + 1 * LL * NRELS, hidden + (size_t)1 * LL * E,
                                            hx0, sB, 0);
    prop_kernel<<<B * LL, 256, 0, stream>>>(sB, heads, tails, rels, ent,
                                            wp + 2 * LL * NRELS, hidden + (size_t)2 * LL * E,
                                            hx0, sA, 0);

    out_kernel<<<(B * E + 255) / 256, 256, 0, stream>>>(sA, tanhw, (float*)d_out);
}

// Round 2
// 250.092 us; speedup vs baseline: 1.1007x; 1.1007x over previous
//
#include <hip/hip_runtime.h>

#define B 8
#define E 2000
#define NTRI 10000
#define NRELS 25
#define KT 16
#define TT 3
#define LL 32
#define TAU1 10.0f

__device__ __forceinline__ float clip01(float x) { return fminf(fmaxf(x, 0.0f), 1.0f); }

// ---------------------------------------------------------------------------
// K1: one pass over all dense one-hot inputs.
//  - e2triple [E,NTRI]: nonzero at (head, j)  -> packed[j] |= head        (bits 0..10)
//  - triple2e [NTRI,E]: nonzero at (j, tail)  -> probe triple2r row j for rel r,
//        packed[j] |= tail<<11 | r<<22 (bits 11..26); mask[tail] |= 1<<r (r<24)
//  - input_x  [B,E]   : ent[b] = col
//  - type_mat [E,KT]  : tidx[e] = col
//  - zero d_out (B*E floats) so prop t=2 can atomicAdd into it
// ---------------------------------------------------------------------------
__global__ void extract_all(const float4* __restrict__ e2t, const float4* __restrict__ t2e,
                            const float* __restrict__ t2r, const float4* __restrict__ ix,
                            const float4* __restrict__ tm,
                            unsigned int* __restrict__ packed, unsigned int* __restrict__ mask,
                            int* __restrict__ ent, int* __restrict__ tidx,
                            float4* __restrict__ out4) {
    const int gtid = blockIdx.x * blockDim.x + threadIdx.x;
    const int gs = gridDim.x * blockDim.x;

    // e2triple: 2000*10000 floats = 5,000,000 float4
    for (int i = gtid; i < E * NTRI / 4; i += gs) {
        float4 v = e2t[i];
        if (v.x != 0.0f || v.y != 0.0f || v.z != 0.0f || v.w != 0.0f) {
            int f = i * 4;
#pragma unroll
            for (int k = 0; k < 4; k++) {
                float c = (k == 0) ? v.x : (k == 1) ? v.y : (k == 2) ? v.z : v.w;
                if (c != 0.0f) {
                    int a = f + k;
                    int head = a / NTRI;
                    int j = a - head * NTRI;
                    atomicOr(&packed[j], (unsigned int)head);
                }
            }
        }
    }

    // triple2e: 10000*2000 floats = 5,000,000 float4
    for (int i = gtid; i < NTRI * E / 4; i += gs) {
        float4 v = t2e[i];
        if (v.x != 0.0f || v.y != 0.0f || v.z != 0.0f || v.w != 0.0f) {
            int f = i * 4;
#pragma unroll
            for (int k = 0; k < 4; k++) {
                float c = (k == 0) ? v.x : (k == 1) ? v.y : (k == 2) ? v.z : v.w;
                if (c != 0.0f) {
                    int a = f + k;
                    int j = a / E;
                    int tail = a - j * E;
                    int r = 0;
                    while (r < NRELS - 1 && t2r[j * NRELS + r] == 0.0f) r++;
                    atomicOr(&packed[j], ((unsigned int)tail << 11) | ((unsigned int)r << 22));
                    if (r < NRELS - 1) atomicOr(&mask[tail], 1u << r);
                }
            }
        }
    }

    // input_x: 8*2000 = 4000 float4
    for (int i = gtid; i < B * E / 4; i += gs) {
        float4 v = ix[i];
        if (v.x != 0.0f || v.y != 0.0f || v.z != 0.0f || v.w != 0.0f) {
            int f = i * 4;
#pragma unroll
            for (int k = 0; k < 4; k++) {
                float c = (k == 0) ? v.x : (k == 1) ? v.y : (k == 2) ? v.z : v.w;
                if (c != 0.0f) { int a = f + k; int b = a / E; ent[b] = a - b * E; }
            }
        }
    }

    // type_mat: 2000*16 = 8000 float4
    for (int i = gtid; i < E * KT / 4; i += gs) {
        float4 v = tm[i];
        if (v.x != 0.0f || v.y != 0.0f || v.z != 0.0f || v.w != 0.0f) {
            int f = i * 4;
#pragma unroll
            for (int k = 0; k < 4; k++) {
                float c = (k == 0) ? v.x : (k == 1) ? v.y : (k == 2) ? v.z : v.w;
                if (c != 0.0f) { int a = f + k; int e = a / KT; tidx[e] = a - e * KT; }
            }
        }
    }

    // zero d_out
    float4 z = make_float4(0.f, 0.f, 0.f, 0.f);
    for (int i = gtid; i < B * E / 4; i += gs) out4[i] = z;
}

// ---------------------------------------------------------------------------
// One block per (b,l). Does softmax(w[t,l]) + sparse propagate + on-the-fly
// hidden[t][l,e] + (t=0) hidden_x scale + (t=2) fused l-reduction into out.
// ---------------------------------------------------------------------------
__global__ void __launch_bounds__(256) prop(
        const float* __restrict__ sprev, const unsigned int* __restrict__ packed,
        const int* __restrict__ ent, const int* __restrict__ tidx,
        const unsigned int* __restrict__ mask,
        const float* __restrict__ w, const float* __restrict__ h,
        const float* __restrict__ h_type, const float* __restrict__ alpha,
        const float* __restrict__ beta, const float* __restrict__ h_x,
        const float* __restrict__ h_x_type, const float* __restrict__ alpha_x,
        const float* __restrict__ beta_x, const float* __restrict__ weight,
        float* __restrict__ sout, float* __restrict__ out, int t) {
    __shared__ float prev[E];
    __shared__ float acc[E];
    __shared__ float wrow[NRELS];
    __shared__ float hp[NRELS - 1];
    __shared__ float htpL[KT];
    __shared__ unsigned int relflag;

    const int blk = blockIdx.x, b = blk >> 5, l = blk & 31, tid = threadIdx.x;
    const int ent_b = ent[b];
    const int tl = t * LL + l;

    if (t != 0) {
        const float* sp = sprev + (size_t)blk * E;
        for (int e = tid; e < E; e += 256) prev[e] = sp[e];
    }
    for (int e = tid; e < E; e += 256) acc[e] = 0.0f;
    if (tid == 0) {
        relflag = 0u;
        const float* wr = w + tl * NRELS;
        float mx = wr[0];
        for (int r = 1; r < NRELS; r++) mx = fmaxf(mx, wr[r]);
        float ex[NRELS], s = 0.0f;
        for (int r = 0; r < NRELS; r++) { ex[r] = expf(wr[r] - mx); s += ex[r]; }
        float inv = 1.0f / s;
        for (int r = 0; r < NRELS; r++) wrow[r] = ex[r] * inv;
    }
    if (tid < NRELS - 1) hp[tid] = clip01(h[tl * (NRELS - 1) + tid] / TAU1);
    if (tid < KT) htpL[tid] = clip01(h_type[tl * KT + tid] / TAU1);
    __syncthreads();

    const uint4* p4 = (const uint4*)packed;
    if (t == 0) {
        for (int i = tid; i < NTRI / 4; i += 256) {
            uint4 p = p4[i];
#pragma unroll
            for (int k = 0; k < 4; k++) {
                unsigned int pk = (k == 0) ? p.x : (k == 1) ? p.y : (k == 2) ? p.z : p.w;
                int head = pk & 2047;
                if (head == ent_b) {
                    unsigned int r = pk >> 22;
                    int tail = (pk >> 11) & 2047;
                    atomicAdd(&acc[tail], wrow[r]);
                    atomicOr(&relflag, 1u << r);
                }
            }
        }
    } else {
        for (int i = tid; i < NTRI / 4; i += 256) {
            uint4 p = p4[i];
#pragma unroll
            for (int k = 0; k < 4; k++) {
                unsigned int pk = (k == 0) ? p.x : (k == 1) ? p.y : (k == 2) ? p.z : p.w;
                float pv = prev[pk & 2047];
                if (pv != 0.0f) {
                    unsigned int r = pk >> 22;
                    int tail = (pk >> 11) & 2047;
                    atomicAdd(&acc[tail], pv * wrow[r]);
                }
            }
        }
    }
    __syncthreads();

    const float a = clip01(alpha[tl] / TAU1);
    const float bb = clip01(beta[tl] / TAU1);
    const float base = 1.0f - clip01(a + bb);

    float extra = 1.0f;
    if (t == 0) {
        unsigned int fl = relflag;
        float hxlin = 0.0f;
        for (int i = 0; i < NRELS - 1; i++) {
            int pi = (i < 12) ? (12 + i) : (i - 12);  // concat(hx_raw[:,12:24], hx_raw[:,0:12])
            if ((fl >> pi) & 1u) hxlin += clip01(h_x[l * (NRELS - 1) + i] / TAU1);
        }
        float htx = clip01(h_x_type[l * KT + tidx[ent_b]] / TAU1);
        float ax = clip01(alpha_x[l] / TAU1), bx = clip01(beta_x[l] / TAU1);
        extra = clip01(a * htx + bb * hxlin) + (1.0f - clip01(ax + bx));
    }

    if (t == 2) {
        float tw = tanhf(weight[l]);
        for (int e = tid; e < E; e += 256) {
            unsigned int m = mask[e];
            float dot = 0.0f;
#pragma unroll
            for (int i = 0; i < NRELS - 1; i++) dot += ((m >> i) & 1u) ? hp[i] : 0.0f;
            float he = clip01(a * htpL[tidx[e]] + bb * dot) + base;
            atomicAdd(&out[b * E + e], acc[e] * he * tw);
        }
    } else {
        float* so = sout + (size_t)blk * E;
        for (int e = tid; e < E; e += 256) {
            unsigned int m = mask[e];
            float dot = 0.0f;
#pragma unroll
            for (int i = 0; i < NRELS - 1; i++) dot += ((m >> i) & 1u) ? hp[i] : 0.0f;
            float he = clip01(a * htpL[tidx[e]] + bb * dot) + base;
            so[e] = acc[e] * he * extra;
        }
    }
}

extern "C" void kernel_launch(void* const* d_in, const int* in_sizes, int n_in,
                              void* d_out, int out_size, void* d_ws, size_t ws_size,
                              hipStream_t stream) {
    const float* input_x  = (const float*)d_in[0];
    const float* type_mat = (const float*)d_in[1];
    const float* e2triple = (const float*)d_in[2];
    const float* triple2e = (const float*)d_in[3];
    const float* triple2r = (const float*)d_in[4];
    const float* w        = (const float*)d_in[5];
    const float* weight   = (const float*)d_in[6];
    const float* h        = (const float*)d_in[7];
    const float* h_x      = (const float*)d_in[8];
    const float* h_type   = (const float*)d_in[9];
    const float* h_x_type = (const float*)d_in[10];
    const float* alpha    = (const float*)d_in[11];
    const float* beta     = (const float*)d_in[12];
    const float* alpha_x  = (const float*)d_in[13];
    const float* beta_x   = (const float*)d_in[14];
    (void)in_sizes; (void)n_in; (void)out_size; (void)ws_size;

    char* ws = (char*)d_ws;
    size_t off = 0;
    auto alloc = [&](size_t bytes) -> void* {
        void* p = ws + off;
        off += (bytes + 255) & ~(size_t)255;
        return p;
    };
    unsigned int* packed = (unsigned int*)alloc(NTRI * sizeof(unsigned int));  // 40000
    unsigned int* maskp  = (unsigned int*)alloc(E * sizeof(unsigned int));     // 8000
    size_t zero_bytes = off;  // packed+mask must start at 0 (atomicOr targets)
    int*   ent  = (int*)alloc(B * sizeof(int));
    int*   tidx = (int*)alloc(E * sizeof(int));
    float* sA   = (float*)alloc((size_t)B * LL * E * sizeof(float));
    float* sB   = (float*)alloc((size_t)B * LL * E * sizeof(float));

    hipMemsetAsync(ws, 0, zero_bytes, stream);

    extract_all<<<8192, 256, 0, stream>>>((const float4*)e2triple, (const float4*)triple2e,
                                          triple2r, (const float4*)input_x, (const float4*)type_mat,
                                          packed, maskp, ent, tidx, (float4*)d_out);

    prop<<<B * LL, 256, 0, stream>>>(nullptr, packed, ent, tidx, maskp, w, h, h_type,
                                     alpha, beta, h_x, h_x_type, alpha_x, beta_x, weight,
                                     sA, (float*)d_out, 0);
    prop<<<B * LL, 256, 0, stream>>>(sA, packed, ent, tidx, maskp, w, h, h_type,
                                     alpha, beta, h_x, h_x_type, alpha_x, beta_x, weight,
                                     sB, (float*)d_out, 1);
    prop<<<B * LL, 256, 0, stream>>>(sB, packed, ent, tidx, maskp, w, h, h_type,
                                     alpha, beta, h_x, h_x_type, alpha_x, beta_x, weight,
                                     nullptr, (float*)d_out, 2);
}

// Round 3
// 243.991 us; speedup vs baseline: 1.1282x; 1.0250x over previous
//
#include <hip/hip_runtime.h>

#define B 8
#define E 2000
#define NTRI 10000
#define NRELS 25
#define KT 16
#define TT 3
#define LL 32
#define TAU1 10.0f
#define XBLK 2048
#define XTHR 256

__device__ __forceinline__ float clip01(float x) { return fminf(fmaxf(x, 0.0f), 1.0f); }

__device__ __forceinline__ void proc_e2t(float4 v, int i, unsigned int* packed) {
    if (v.x == 0.f && v.y == 0.f && v.z == 0.f && v.w == 0.f) return;
    int f = i * 4;
    float c[4] = {v.x, v.y, v.z, v.w};
#pragma unroll
    for (int k = 0; k < 4; k++)
        if (c[k] != 0.f) {
            int a = f + k;
            int head = a / NTRI;
            int j = a - head * NTRI;
            atomicOr(&packed[j], (unsigned int)head);
        }
}

__device__ __forceinline__ void proc_t2e(float4 v, int i, const float* __restrict__ t2r,
                                         unsigned int* packed, unsigned int* mask) {
    if (v.x == 0.f && v.y == 0.f && v.z == 0.f && v.w == 0.f) return;
    int f = i * 4;
    float c[4] = {v.x, v.y, v.z, v.w};
#pragma unroll
    for (int k = 0; k < 4; k++)
        if (c[k] != 0.f) {
            int a = f + k;
            int j = a / E;
            int tail = a - j * E;
            const float* row = t2r + j * NRELS;
            int r = 0;
            while (r < NRELS - 1 && row[r] == 0.f) r++;
            atomicOr(&packed[j], ((unsigned int)tail << 11) | ((unsigned int)r << 22));
            if (r < NRELS - 1) atomicOr(&mask[tail], 1u << r);
        }
}

// One pass over all dense one-hots. packed[j] = head | tail<<11 | rel<<22.
// mask[e] = 24-bit rel-flag bitmask of triples with tail==e. Also zeroes d_out.
__global__ void __launch_bounds__(XTHR) extract_all(
        const float4* __restrict__ e2t, const float4* __restrict__ t2e,
        const float* __restrict__ t2r, const float4* __restrict__ ix,
        const float4* __restrict__ tm,
        unsigned int* __restrict__ packed, unsigned int* __restrict__ mask,
        int* __restrict__ ent, int* __restrict__ tidx, float4* __restrict__ out4) {
    const int gtid = blockIdx.x * XTHR + threadIdx.x;
    const int gs = XBLK * XTHR;

    // input_x [B,E]: ent[b] = col  (4000 float4)
    for (int i = gtid; i < B * E / 4; i += gs) {
        float4 v = ix[i];
        if (v.x != 0.f || v.y != 0.f || v.z != 0.f || v.w != 0.f) {
            int f = i * 4;
            float c[4] = {v.x, v.y, v.z, v.w};
#pragma unroll
            for (int k = 0; k < 4; k++)
                if (c[k] != 0.f) { int a = f + k; int b = a / E; ent[b] = a - b * E; }
        }
    }
    // type_mat [E,KT]: tidx[e] = col  (8000 float4)
    for (int i = gtid; i < E * KT / 4; i += gs) {
        float4 v = tm[i];
        if (v.x != 0.f || v.y != 0.f || v.z != 0.f || v.w != 0.f) {
            int f = i * 4;
            float c[4] = {v.x, v.y, v.z, v.w};
#pragma unroll
            for (int k = 0; k < 4; k++)
                if (c[k] != 0.f) { int a = f + k; int e = a / KT; tidx[e] = a - e * KT; }
        }
    }
    // zero d_out (4000 float4)
    float4 z = make_float4(0.f, 0.f, 0.f, 0.f);
    for (int i = gtid; i < B * E / 4; i += gs) out4[i] = z;

    // e2triple [E,NTRI] (5M float4), unroll x4 for memory-level parallelism
    {
        const int n4 = E * NTRI / 4;
        for (int i0 = gtid; i0 < n4; i0 += gs * 4) {
            int i1 = i0 + gs, i2 = i0 + 2 * gs, i3 = i0 + 3 * gs;
            float4 v0 = e2t[i0];
            float4 v1 = (i1 < n4) ? e2t[i1] : z;
            float4 v2 = (i2 < n4) ? e2t[i2] : z;
            float4 v3 = (i3 < n4) ? e2t[i3] : z;
            proc_e2t(v0, i0, packed);
            proc_e2t(v1, i1, packed);
            proc_e2t(v2, i2, packed);
            proc_e2t(v3, i3, packed);
        }
    }
    // triple2e [NTRI,E] (5M float4), unroll x4
    {
        const int n4 = NTRI * E / 4;
        for (int i0 = gtid; i0 < n4; i0 += gs * 4) {
            int i1 = i0 + gs, i2 = i0 + 2 * gs, i3 = i0 + 3 * gs;
            float4 v0 = t2e[i0];
            float4 v1 = (i1 < n4) ? t2e[i1] : z;
            float4 v2 = (i2 < n4) ? t2e[i2] : z;
            float4 v3 = (i3 < n4) ? t2e[i3] : z;
            proc_t2e(v0, i0, t2r, packed, mask);
            proc_t2e(v1, i1, t2r, packed, mask);
            proc_t2e(v2, i2, t2r, packed, mask);
            proc_t2e(v3, i3, t2r, packed, mask);
        }
    }
}

// One block per (b,l); all TT rounds internally, s stays in LDS.
// t=2 fuses the l-reduction via global fp32 atomics into out (pre-zeroed).
__global__ void __launch_bounds__(512) mega_prop(
        const unsigned int* __restrict__ packed, const int* __restrict__ ent,
        const int* __restrict__ tidx, const unsigned int* __restrict__ mask,
        const float* __restrict__ w, const float* __restrict__ h,
        const float* __restrict__ h_type, const float* __restrict__ alpha,
        const float* __restrict__ beta, const float* __restrict__ h_x,
        const float* __restrict__ h_x_type, const float* __restrict__ alpha_x,
        const float* __restrict__ beta_x, const float* __restrict__ weight,
        float* __restrict__ out) {
    __shared__ float prev[E];
    __shared__ float acc[E];
    __shared__ unsigned int mask_s[E];
    __shared__ int tidx_s[E];
    __shared__ float wrow[NRELS];
    __shared__ float hp[NRELS - 1];
    __shared__ float htpL[KT];
    __shared__ unsigned int relflag;
    __shared__ float extra_s;

    const int NT = 512;
    const int blk = blockIdx.x, b = blk >> 5, l = blk & 31, tid = threadIdx.x;
    const int ent_b = ent[b];

    for (int e = tid; e < E; e += NT) {
        acc[e] = 0.f;
        mask_s[e] = mask[e];
        tidx_s[e] = tidx[e];
    }
    if (tid == 0) { relflag = 0u; extra_s = 1.f; }

    const uint4* p4 = (const uint4*)packed;

    for (int t = 0; t < TT; t++) {
        const int tl = t * LL + l;
        // per-round params (disjoint thread groups; sync below)
        if (tid == 0) {
            const float* wr = w + tl * NRELS;
            float mx = wr[0];
            for (int r = 1; r < NRELS; r++) mx = fmaxf(mx, wr[r]);
            float ex[NRELS], s = 0.f;
            for (int r = 0; r < NRELS; r++) { ex[r] = expf(wr[r] - mx); s += ex[r]; }
            float inv = 1.f / s;
            for (int r = 0; r < NRELS; r++) wrow[r] = ex[r] * inv;
        }
        if (tid >= 64 && tid < 64 + NRELS - 1)
            hp[tid - 64] = clip01(h[tl * (NRELS - 1) + (tid - 64)] / TAU1);
        if (tid >= 128 && tid < 128 + KT)
            htpL[tid - 128] = clip01(h_type[tl * KT + (tid - 128)] / TAU1);
        __syncthreads();

        if (t == 0) {
            for (int i = tid; i < NTRI / 4; i += NT) {
                uint4 p = p4[i];
#pragma unroll
                for (int k = 0; k < 4; k++) {
                    unsigned int pk = (k == 0) ? p.x : (k == 1) ? p.y : (k == 2) ? p.z : p.w;
                    if ((int)(pk & 2047u) == ent_b) {
                        unsigned int r = pk >> 22;
                        int tail = (pk >> 11) & 2047;
                        atomicAdd(&acc[tail], wrow[r]);
                        atomicOr(&relflag, 1u << r);
                    }
                }
            }
        } else {
            for (int i = tid; i < NTRI / 4; i += NT) {
                uint4 p = p4[i];
#pragma unroll
                for (int k = 0; k < 4; k++) {
                    unsigned int pk = (k == 0) ? p.x : (k == 1) ? p.y : (k == 2) ? p.z : p.w;
                    float pv = prev[pk & 2047u];
                    if (pv != 0.f) {
                        unsigned int r = pk >> 22;
                        int tail = (pk >> 11) & 2047;
                        atomicAdd(&acc[tail], pv * wrow[r]);
                    }
                }
            }
        }
        __syncthreads();

        const float a = clip01(alpha[tl] / TAU1);
        const float bb = clip01(beta[tl] / TAU1);
        const float base = 1.f - clip01(a + bb);

        if (t == 0 && tid == 0) {
            unsigned int fl = relflag;
            float hxlin = 0.f;
            for (int i = 0; i < NRELS - 1; i++) {
                int pi = (i < 12) ? (12 + i) : (i - 12);  // concat(hx_raw[:,12:24], hx_raw[:,0:12])
                if ((fl >> pi) & 1u) hxlin += clip01(h_x[l * (NRELS - 1) + i] / TAU1);
            }
            float htx = clip01(h_x_type[l * KT + tidx_s[ent_b]] / TAU1);
            float ax = clip01(alpha_x[l] / TAU1), bx = clip01(beta_x[l] / TAU1);
            extra_s = clip01(a * htx + bb * hxlin) + (1.f - clip01(ax + bx));
        }
        __syncthreads();

        const float extra = (t == 0) ? extra_s : 1.f;

        if (t < TT - 1) {
            for (int e = tid; e < E; e += NT) {
                unsigned int m = mask_s[e];
                float dot = 0.f;
#pragma unroll
                for (int i = 0; i < NRELS - 1; i++) dot += ((m >> i) & 1u) ? hp[i] : 0.f;
                float he = clip01(a * htpL[tidx_s[e]] + bb * dot) + base;
                prev[e] = acc[e] * he * extra;
                acc[e] = 0.f;
            }
        } else {
            float tw = tanhf(weight[l]);
            for (int e = tid; e < E; e += NT) {
                unsigned int m = mask_s[e];
                float dot = 0.f;
#pragma unroll
                for (int i = 0; i < NRELS - 1; i++) dot += ((m >> i) & 1u) ? hp[i] : 0.f;
                float he = clip01(a * htpL[tidx_s[e]] + bb * dot) + base;
                atomicAdd(&out[b * E + e], acc[e] * he * tw);
            }
        }
        __syncthreads();
    }
}

extern "C" void kernel_launch(void* const* d_in, const int* in_sizes, int n_in,
                              void* d_out, int out_size, void* d_ws, size_t ws_size,
                              hipStream_t stream) {
    const float* input_x  = (const float*)d_in[0];
    const float* type_mat = (const float*)d_in[1];
    const float* e2triple = (const float*)d_in[2];
    const float* triple2e = (const float*)d_in[3];
    const float* triple2r = (const float*)d_in[4];
    const float* w        = (const float*)d_in[5];
    const float* weight   = (const float*)d_in[6];
    const float* h        = (const float*)d_in[7];
    const float* h_x      = (const float*)d_in[8];
    const float* h_type   = (const float*)d_in[9];
    const float* h_x_type = (const float*)d_in[10];
    const float* alpha    = (const float*)d_in[11];
    const float* beta     = (const float*)d_in[12];
    const float* alpha_x  = (const float*)d_in[13];
    const float* beta_x   = (const float*)d_in[14];
    (void)in_sizes; (void)n_in; (void)out_size; (void)ws_size;

    char* ws = (char*)d_ws;
    size_t off = 0;
    auto alloc = [&](size_t bytes) -> void* {
        void* p = ws + off;
        off += (bytes + 255) & ~(size_t)255;
        return p;
    };
    unsigned int* packed = (unsigned int*)alloc(NTRI * sizeof(unsigned int));
    unsigned int* maskp  = (unsigned int*)alloc(E * sizeof(unsigned int));
    size_t zero_bytes = off;  // atomicOr targets must start at 0
    int* ent  = (int*)alloc(B * sizeof(int));
    int* tidx = (int*)alloc(E * sizeof(int));

    hipMemsetAsync(ws, 0, zero_bytes, stream);

    extract_all<<<XBLK, XTHR, 0, stream>>>((const float4*)e2triple, (const float4*)triple2e,
                                           triple2r, (const float4*)input_x,
                                           (const float4*)type_mat,
                                           packed, maskp, ent, tidx, (float4*)d_out);

    mega_prop<<<B * LL, 512, 0, stream>>>(packed, ent, tidx, maskp, w, h, h_type,
                                          alpha, beta, h_x, h_x_type, alpha_x, beta_x,
                                          weight, (float*)d_out);
}

// Round 4
// 223.205 us; speedup vs baseline: 1.2332x; 1.0931x over previous
//
#include <hip/hip_runtime.h>

#define B 8
#define E 2000
#define NTRI 10000
#define NRELS 25
#define KT 16
#define TT 3
#define LL 32
#define TAU1 10.0f
#define XBLK 8192
#define XTHR 256

__device__ __forceinline__ float clip01(float x) { return fminf(fmaxf(x, 0.0f), 1.0f); }

// One pass over all dense one-hot inputs; every sweep is fully coalesced and
// contains NO data-dependent loads (the old triple2r probe was a serial-latency
// tail: up to 24 dependent scattered loads per nonzero).
// packed[j] = head | tail<<11 | rel<<22  (head,tail < 2048; rel < 32)
__global__ void __launch_bounds__(XTHR) extract_all(
        const float4* __restrict__ e2t, const float4* __restrict__ t2e,
        const float4* __restrict__ t2r, const float4* __restrict__ ix,
        const float4* __restrict__ tm,
        unsigned int* __restrict__ packed,
        int* __restrict__ ent, int* __restrict__ tidx, float4* __restrict__ out4) {
    const int gtid = blockIdx.x * XTHR + threadIdx.x;
    const int gs = XBLK * XTHR;

    // input_x [B,E]: ent[b] = col  (4000 float4)
    for (int i = gtid; i < B * E / 4; i += gs) {
        float4 v = ix[i];
        if (v.x != 0.f || v.y != 0.f || v.z != 0.f || v.w != 0.f) {
            int f = i * 4;
            float c[4] = {v.x, v.y, v.z, v.w};
#pragma unroll
            for (int k = 0; k < 4; k++)
                if (c[k] != 0.f) { int a = f + k; int b = a / E; ent[b] = a - b * E; }
        }
    }
    // type_mat [E,KT]: tidx[e] = col  (8000 float4)
    for (int i = gtid; i < E * KT / 4; i += gs) {
        float4 v = tm[i];
        if (v.x != 0.f || v.y != 0.f || v.z != 0.f || v.w != 0.f) {
            int f = i * 4;
            float c[4] = {v.x, v.y, v.z, v.w};
#pragma unroll
            for (int k = 0; k < 4; k++)
                if (c[k] != 0.f) { int a = f + k; int e = a / KT; tidx[e] = a - e * KT; }
        }
    }
    // zero d_out (4000 float4)
    float4 z = make_float4(0.f, 0.f, 0.f, 0.f);
    for (int i = gtid; i < B * E / 4; i += gs) out4[i] = z;

    // triple2r [NTRI,NRELS] (62500 float4): rel field
    for (int i = gtid; i < NTRI * NRELS / 4; i += gs) {
        float4 v = t2r[i];
        if (v.x != 0.f || v.y != 0.f || v.z != 0.f || v.w != 0.f) {
            int f = i * 4;
            float c[4] = {v.x, v.y, v.z, v.w};
#pragma unroll
            for (int k = 0; k < 4; k++)
                if (c[k] != 0.f) {
                    int a = f + k;
                    int j = a / NRELS;
                    unsigned int r = a - j * NRELS;
                    atomicOr(&packed[j], r << 22);
                }
        }
    }
    // e2triple [E,NTRI] (5M float4): head field
    for (int i = gtid; i < E * NTRI / 4; i += gs) {
        float4 v = e2t[i];
        if (v.x != 0.f || v.y != 0.f || v.z != 0.f || v.w != 0.f) {
            int f = i * 4;
            float c[4] = {v.x, v.y, v.z, v.w};
#pragma unroll
            for (int k = 0; k < 4; k++)
                if (c[k] != 0.f) {
                    int a = f + k;
                    int head = a / NTRI;
                    int j = a - head * NTRI;
                    atomicOr(&packed[j], (unsigned int)head);
                }
        }
    }
    // triple2e [NTRI,E] (5M float4): tail field
    for (int i = gtid; i < NTRI * E / 4; i += gs) {
        float4 v = t2e[i];
        if (v.x != 0.f || v.y != 0.f || v.z != 0.f || v.w != 0.f) {
            int f = i * 4;
            float c[4] = {v.x, v.y, v.z, v.w};
#pragma unroll
            for (int k = 0; k < 4; k++)
                if (c[k] != 0.f) {
                    int a = f + k;
                    int j = a / E;
                    unsigned int tail = a - j * E;
                    atomicOr(&packed[j], tail << 11);
                }
        }
    }
}

// One block per (b,l); all TT rounds internally, s stays in LDS.
// mask (tail-rel existence bitmask) is built per-block in LDS during the t=0
// scan of packed. t=2 fuses the l-reduction via global fp32 atomics into out.
__global__ void __launch_bounds__(512) mega_prop(
        const unsigned int* __restrict__ packed, const int* __restrict__ ent,
        const int* __restrict__ tidx,
        const float* __restrict__ w, const float* __restrict__ h,
        const float* __restrict__ h_type, const float* __restrict__ alpha,
        const float* __restrict__ beta, const float* __restrict__ h_x,
        const float* __restrict__ h_x_type, const float* __restrict__ alpha_x,
        const float* __restrict__ beta_x, const float* __restrict__ weight,
        float* __restrict__ out) {
    __shared__ float prev[E];
    __shared__ float acc[E];
    __shared__ unsigned int mask_s[E];
    __shared__ int tidx_s[E];
    __shared__ float wrow[NRELS];
    __shared__ float hp[NRELS - 1];
    __shared__ float htpL[KT];
    __shared__ unsigned int relflag;
    __shared__ float extra_s;

    const int NT = 512;
    const int blk = blockIdx.x, b = blk >> 5, l = blk & 31, tid = threadIdx.x;
    const int ent_b = ent[b];

    for (int e = tid; e < E; e += NT) {
        acc[e] = 0.f;
        mask_s[e] = 0u;
        tidx_s[e] = tidx[e];
    }
    if (tid == 0) { relflag = 0u; extra_s = 1.f; }

    const uint4* p4 = (const uint4*)packed;

    for (int t = 0; t < TT; t++) {
        const int tl = t * LL + l;
        if (tid == 0) {
            const float* wr = w + tl * NRELS;
            float mx = wr[0];
            for (int r = 1; r < NRELS; r++) mx = fmaxf(mx, wr[r]);
            float ex[NRELS], s = 0.f;
            for (int r = 0; r < NRELS; r++) { ex[r] = expf(wr[r] - mx); s += ex[r]; }
            float inv = 1.f / s;
            for (int r = 0; r < NRELS; r++) wrow[r] = ex[r] * inv;
        }
        if (tid >= 64 && tid < 64 + NRELS - 1)
            hp[tid - 64] = clip01(h[tl * (NRELS - 1) + (tid - 64)] / TAU1);
        if (tid >= 128 && tid < 128 + KT)
            htpL[tid - 128] = clip01(h_type[tl * KT + (tid - 128)] / TAU1);
        __syncthreads();

        if (t == 0) {
            for (int i = tid; i < NTRI / 4; i += NT) {
                uint4 p = p4[i];
#pragma unroll
                for (int k = 0; k < 4; k++) {
                    unsigned int pk = (k == 0) ? p.x : (k == 1) ? p.y : (k == 2) ? p.z : p.w;
                    unsigned int r = pk >> 22;
                    int tail = (pk >> 11) & 2047;
                    if (r < NRELS - 1) atomicOr(&mask_s[tail], 1u << r);  // hidden_base flags
                    if ((int)(pk & 2047u) == ent_b) {
                        atomicAdd(&acc[tail], wrow[r]);
                        atomicOr(&relflag, 1u << r);
                    }
                }
            }
        } else {
            for (int i = tid; i < NTRI / 4; i += NT) {
                uint4 p = p4[i];
#pragma unroll
                for (int k = 0; k < 4; k++) {
                    unsigned int pk = (k == 0) ? p.x : (k == 1) ? p.y : (k == 2) ? p.z : p.w;
                    float pv = prev[pk & 2047u];
                    if (pv != 0.f) {
                        unsigned int r = pk >> 22;
                        int tail = (pk >> 11) & 2047;
                        atomicAdd(&acc[tail], pv * wrow[r]);
                    }
                }
            }
        }
        __syncthreads();

        const float a = clip01(alpha[tl] / TAU1);
        const float bb = clip01(beta[tl] / TAU1);
        const float base = 1.f - clip01(a + bb);

        if (t == 0 && tid == 0) {
            unsigned int fl = relflag;
            float hxlin = 0.f;
            for (int i = 0; i < NRELS - 1; i++) {
                int pi = (i < 12) ? (12 + i) : (i - 12);  // concat(hx_raw[:,12:24], hx_raw[:,0:12])
                if ((fl >> pi) & 1u) hxlin += clip01(h_x[l * (NRELS - 1) + i] / TAU1);
            }
            float htx = clip01(h_x_type[l * KT + tidx_s[ent_b]] / TAU1);
            float ax = clip01(alpha_x[l] / TAU1), bx = clip01(beta_x[l] / TAU1);
            extra_s = clip01(a * htx + bb * hxlin) + (1.f - clip01(ax + bx));
        }
        __syncthreads();

        const float extra = (t == 0) ? extra_s : 1.f;

        if (t < TT - 1) {
            for (int e = tid; e < E; e += NT) {
                unsigned int m = mask_s[e];
                float dot = 0.f;
#pragma unroll
                for (int i = 0; i < NRELS - 1; i++) dot += ((m >> i) & 1u) ? hp[i] : 0.f;
                float he = clip01(a * htpL[tidx_s[e]] + bb * dot) + base;
                prev[e] = acc[e] * he * extra;
                acc[e] = 0.f;
            }
        } else {
            float tw = tanhf(weight[l]);
            for (int e = tid; e < E; e += NT) {
                unsigned int m = mask_s[e];
                float dot = 0.f;
#pragma unroll
                for (int i = 0; i < NRELS - 1; i++) dot += ((m >> i) & 1u) ? hp[i] : 0.f;
                float he = clip01(a * htpL[tidx_s[e]] + bb * dot) + base;
                atomicAdd(&out[b * E + e], acc[e] * he * tw);
            }
        }
        __syncthreads();
    }
}

extern "C" void kernel_launch(void* const* d_in, const int* in_sizes, int n_in,
                              void* d_out, int out_size, void* d_ws, size_t ws_size,
                              hipStream_t stream) {
    const float* input_x  = (const float*)d_in[0];
    const float* type_mat = (const float*)d_in[1];
    const float* e2triple = (const float*)d_in[2];
    const float* triple2e = (const float*)d_in[3];
    const float* triple2r = (const float*)d_in[4];
    const float* w        = (const float*)d_in[5];
    const float* weight   = (const float*)d_in[6];
    const float* h        = (const float*)d_in[7];
    const float* h_x      = (const float*)d_in[8];
    const float* h_type   = (const float*)d_in[9];
    const float* h_x_type = (const float*)d_in[10];
    const float* alpha    = (const float*)d_in[11];
    const float* beta     = (const float*)d_in[12];
    const float* alpha_x  = (const float*)d_in[13];
    const float* beta_x   = (const float*)d_in[14];
    (void)in_sizes; (void)n_in; (void)out_size; (void)ws_size;

    char* ws = (char*)d_ws;
    unsigned int* packed = (unsigned int*)ws;                    // NTRI u32, must be 0
    int* ent  = (int*)(ws + ((NTRI * 4 + 255) & ~255));
    int* tidx = ent + 64;  // 256B-aligned enough (ent uses 8 ints)

    hipMemsetAsync(packed, 0, NTRI * sizeof(unsigned int), stream);

    extract_all<<<XBLK, XTHR, 0, stream>>>((const float4*)e2triple, (const float4*)triple2e,
                                           (const float4*)triple2r, (const float4*)input_x,
                                           (const float4*)type_mat,
                                           packed, ent, tidx, (float4*)d_out);

    mega_prop<<<B * LL, 512, 0, stream>>>(packed, ent, tidx, w, h, h_type,
                                          alpha, beta, h_x, h_x_type, alpha_x, beta_x,
                                          weight, (float*)d_out);
}